// Round 1
// baseline (444.065 us; speedup 1.0000x reference)
//
#include <hip/hip_runtime.h>
#include <hip/hip_bf16.h>
#include <stdint.h>

#define B_  4
#define N_  2048
#define C_  1024
#define H_  16
#define HD_ 64
#define M_  (B_*N_)     // 8192
#define K3_ (3*C_)      // 3072

typedef __bf16 bf16;
typedef __bf16 bf16x8 __attribute__((ext_vector_type(8)));
typedef __bf16 bf16x4 __attribute__((ext_vector_type(4)));
typedef float f32x4 __attribute__((ext_vector_type(4)));

// ---------------- f32 -> bf16 cast ----------------
__global__ void castk(const float* __restrict__ in, bf16* __restrict__ out, int n4) {
    int stride = gridDim.x * blockDim.x;
    for (int i = blockIdx.x * blockDim.x + threadIdx.x; i < n4; i += stride) {
        float4 v = reinterpret_cast<const float4*>(in)[i];
        bf16x4 o;
        o[0] = (bf16)v.x; o[1] = (bf16)v.y; o[2] = (bf16)v.z; o[3] = (bf16)v.w;
        *reinterpret_cast<bf16x4*>(out + (size_t)i * 4) = o;
    }
}

__device__ __forceinline__ void gll16(const bf16* g, const bf16* l) {
    __builtin_amdgcn_global_load_lds(
        (const __attribute__((address_space(1))) void*)g,
        (__attribute__((address_space(3))) void*)l, 16, 0, 0);
}

// ---------------- GEMM  out[m][n] = sum_k A[m][k] * B[n][k] ----------------
// MODE 0: A=x_bf16[8192][1024], B=w_qkv[3072][1024]; epilogue: RoPE on q,k
//         (q scaled by 0.125), scatter to q/k/v [B][H][N][HD] bf16.
// MODE 1: A=attn_out[8192][1024], B=w_proj[1024][1024]; epilogue: +bias, f32 out.
template<int MODE>
__global__ __launch_bounds__(256, 2)
void gemm_bt(const bf16* __restrict__ A, const bf16* __restrict__ Bm,
             int Nn, int Kk,
             bf16* __restrict__ qout, bf16* __restrict__ kout, bf16* __restrict__ vout,
             const float* __restrict__ fcos, const float* __restrict__ fsin,
             const float* __restrict__ bias, float* __restrict__ Cout)
{
    __shared__ bf16 a_lds[128 * 32];
    __shared__ bf16 b_lds[128 * 32];
    const int tid  = threadIdx.x;
    const int lane = tid & 63;
    const int w    = tid >> 6;        // wave 0..3
    const int wr   = w >> 1, wc = w & 1;  // 2x2 wave grid, 64x64 per wave
    const int ntile = Nn >> 7;
    const int bx = blockIdx.x % ntile, by = blockIdx.x / ntile;
    const int m0 = by * 128, n0 = bx * 128;

    f32x4 acc[4][4] = {};

    // staging: chunk c in {tid, tid+256}; row = c>>2, col-off = (c&3)*8
    const int c0 = tid, c1 = tid + 256;
    const bf16* ga0 = A  + (size_t)(m0 + (c0 >> 2)) * Kk + (c0 & 3) * 8;
    const bf16* ga1 = A  + (size_t)(m0 + (c1 >> 2)) * Kk + (c1 & 3) * 8;
    const bf16* gb0 = Bm + (size_t)(n0 + (c0 >> 2)) * Kk + (c0 & 3) * 8;
    const bf16* gb1 = Bm + (size_t)(n0 + (c1 >> 2)) * Kk + (c1 & 3) * 8;
    const bf16* la0 = a_lds + w * 512;         // wave-uniform LDS bases (bytes: w*1024)
    const bf16* la1 = a_lds + w * 512 + 2048;
    const bf16* lb0 = b_lds + w * 512;
    const bf16* lb1 = b_lds + w * 512 + 2048;

    const int rA = lane & 15;
    const int kk = (lane >> 4) * 8;

    for (int k0 = 0; k0 < Kk; k0 += 32) {
        gll16(ga0 + k0, la0);
        gll16(ga1 + k0, la1);
        gll16(gb0 + k0, lb0);
        gll16(gb1 + k0, lb1);
        __syncthreads();

        bf16x8 af[4], bf[4];
#pragma unroll
        for (int m = 0; m < 4; ++m)
            af[m] = *reinterpret_cast<const bf16x8*>(&a_lds[(wr * 64 + m * 16 + rA) * 32 + kk]);
#pragma unroll
        for (int n = 0; n < 4; ++n)
            bf[n] = *reinterpret_cast<const bf16x8*>(&b_lds[(wc * 64 + n * 16 + rA) * 32 + kk]);
#pragma unroll
        for (int m = 0; m < 4; ++m)
#pragma unroll
            for (int n = 0; n < 4; ++n)
                acc[m][n] = __builtin_amdgcn_mfma_f32_16x16x32_bf16(af[m], bf[n], acc[m][n], 0, 0, 0);
        __syncthreads();
    }

    if (MODE == 1) {
#pragma unroll
        for (int n = 0; n < 4; ++n) {
            int cg = n0 + wc * 64 + n * 16 + (lane & 15);
            float bv = bias[cg];
#pragma unroll
            for (int m = 0; m < 4; ++m) {
                int rg = m0 + wr * 64 + m * 16 + (lane >> 4) * 4;
#pragma unroll
                for (int r = 0; r < 4; ++r)
                    Cout[(size_t)(rg + r) * Nn + cg] = acc[m][n][r] + bv;
            }
        }
    } else {
        const int part = n0 >> 10;   // 0=q 1=k 2=v (block never straddles parts)
#pragma unroll
        for (int n = 0; n < 4; ++n) {
            int cg  = n0 + wc * 64 + n * 16 + (lane & 15);
            int rem = cg & 1023;
            int h   = rem >> 6, hd = rem & 63;
#pragma unroll
            for (int m = 0; m < 4; ++m) {
#pragma unroll
                for (int r = 0; r < 4; ++r) {
                    int rg   = m0 + wr * 64 + m * 16 + (lane >> 4) * 4 + r;
                    int b    = rg >> 11, nrow = rg & 2047;
                    float val = acc[m][n][r];
                    size_t oi = ((size_t)(b * 16 + h) * N_ + nrow) * HD_ + hd;
                    if (part == 2) {
                        vout[oi] = (bf16)val;
                    } else {
                        float p   = __shfl_xor(val, 1);
                        float cth = fcos[nrow * 32 + (hd >> 1)];
                        float sth = fsin[nrow * 32 + (hd >> 1)];
                        float o   = (lane & 1) ? (val * cth + p * sth) : (val * cth - p * sth);
                        if (part == 0) { o *= 0.125f; qout[oi] = (bf16)o; }
                        else           { kout[oi] = (bf16)o; }
                    }
                }
            }
        }
    }
}

// ---------------- flash attention: q/k/v [B*H][N][HD] bf16 -> out [B][N][C] bf16 ----------------
__global__ __launch_bounds__(256, 2)
void attn_kernel(const bf16* __restrict__ Q, const bf16* __restrict__ Kb,
                 const bf16* __restrict__ Vb, bf16* __restrict__ Ob)
{
    __shared__ bf16 k_lds[64 * 72];
    __shared__ bf16 vt_lds[64 * 72];
    __shared__ bf16 p_lds[4][16 * 72];
    const int tid = threadIdx.x, lane = tid & 63, w = tid >> 6;
    const int nqt = N_ / 64;                  // 32
    const int bh = blockIdx.x / nqt, qt = blockIdx.x % nqt;
    const size_t base = (size_t)bh * N_ * HD_;
    const int q0 = qt * 64 + w * 16;
    const int rA = lane & 15, kk = (lane >> 4) * 8;

    bf16x8 qf[2];
    {
        const bf16* qp = Q + base + (size_t)(q0 + rA) * HD_ + kk;
        qf[0] = *reinterpret_cast<const bf16x8*>(qp);
        qf[1] = *reinterpret_cast<const bf16x8*>(qp + 32);
    }

    f32x4 o[4] = {};
    float mrun[4], lrun[4];
#pragma unroll
    for (int r = 0; r < 4; ++r) { mrun[r] = -1e30f; lrun[r] = 0.f; }

    for (int kv0 = 0; kv0 < N_; kv0 += 64) {
        // stage K (row-major, padded) and V transposed
        for (int c = tid; c < 512; c += 256) {
            int row = c >> 3, off = (c & 7) * 8;
            bf16x8 v = *reinterpret_cast<const bf16x8*>(Kb + base + (size_t)(kv0 + row) * HD_ + off);
            *reinterpret_cast<bf16x8*>(&k_lds[row * 72 + off]) = v;
        }
        for (int c = tid; c < 512; c += 256) {
            int row = c >> 3, off = (c & 7) * 8;
            bf16x8 v = *reinterpret_cast<const bf16x8*>(Vb + base + (size_t)(kv0 + row) * HD_ + off);
#pragma unroll
            for (int e = 0; e < 8; ++e) vt_lds[(off + e) * 72 + row] = v[e];
        }
        __syncthreads();

        // S = Q K^T  (q pre-scaled by 1/sqrt(HD))
        f32x4 s[4];
#pragma unroll
        for (int t = 0; t < 4; ++t) {
            bf16x8 b0 = *reinterpret_cast<const bf16x8*>(&k_lds[(t * 16 + rA) * 72 + kk]);
            bf16x8 b1 = *reinterpret_cast<const bf16x8*>(&k_lds[(t * 16 + rA) * 72 + kk + 32]);
            f32x4 z = {};
            z    = __builtin_amdgcn_mfma_f32_16x16x32_bf16(qf[0], b0, z, 0, 0, 0);
            s[t] = __builtin_amdgcn_mfma_f32_16x16x32_bf16(qf[1], b1, z, 0, 0, 0);
        }

        // online softmax (rows live in 16-lane groups)
        float pmax[4];
#pragma unroll
        for (int r = 0; r < 4; ++r)
            pmax[r] = fmaxf(fmaxf(s[0][r], s[1][r]), fmaxf(s[2][r], s[3][r]));
#pragma unroll
        for (int d = 1; d < 16; d <<= 1)
#pragma unroll
            for (int r = 0; r < 4; ++r) pmax[r] = fmaxf(pmax[r], __shfl_xor(pmax[r], d));
        float alpha[4];
#pragma unroll
        for (int r = 0; r < 4; ++r) {
            float nm = fmaxf(mrun[r], pmax[r]);
            alpha[r] = __expf(mrun[r] - nm);
            mrun[r] = nm;
        }
        float psum[4] = {0.f, 0.f, 0.f, 0.f};
#pragma unroll
        for (int t = 0; t < 4; ++t)
#pragma unroll
            for (int r = 0; r < 4; ++r) {
                float p = __expf(s[t][r] - mrun[r]);
                s[t][r] = p;
                psum[r] += p;
            }
#pragma unroll
        for (int d = 1; d < 16; d <<= 1)
#pragma unroll
            for (int r = 0; r < 4; ++r) psum[r] += __shfl_xor(psum[r], d);
#pragma unroll
        for (int r = 0; r < 4; ++r) lrun[r] = lrun[r] * alpha[r] + psum[r];
#pragma unroll
        for (int n = 0; n < 4; ++n)
#pragma unroll
            for (int r = 0; r < 4; ++r) o[n][r] *= alpha[r];

        // P -> LDS (bf16), per-wave region
#pragma unroll
        for (int t = 0; t < 4; ++t)
#pragma unroll
            for (int r = 0; r < 4; ++r)
                p_lds[w][((lane >> 4) * 4 + r) * 72 + t * 16 + (lane & 15)] = (bf16)s[t][r];

        // O += P V
#pragma unroll
        for (int kf = 0; kf < 2; ++kf) {
            bf16x8 pa = *reinterpret_cast<const bf16x8*>(&p_lds[w][rA * 72 + kf * 32 + kk]);
#pragma unroll
            for (int n = 0; n < 4; ++n) {
                bf16x8 vb = *reinterpret_cast<const bf16x8*>(&vt_lds[(n * 16 + rA) * 72 + kf * 32 + kk]);
                o[n] = __builtin_amdgcn_mfma_f32_16x16x32_bf16(pa, vb, o[n], 0, 0, 0);
            }
        }
        __syncthreads();
    }

    // epilogue: divide by row sum, write [B][N][H*HD]
    const int b = bh >> 4, h = bh & 15;
#pragma unroll
    for (int r = 0; r < 4; ++r) {
        int qrow  = qt * 64 + w * 16 + (lane >> 4) * 4 + r;
        float inv = 1.0f / lrun[r];
#pragma unroll
        for (int n = 0; n < 4; ++n) {
            int dcol = n * 16 + (lane & 15);
            Ob[((size_t)(b * N_ + qrow)) * C_ + h * HD_ + dcol] = (bf16)(o[n][r] * inv);
        }
    }
}

extern "C" void kernel_launch(void* const* d_in, const int* in_sizes, int n_in,
                              void* d_out, int out_size, void* d_ws, size_t ws_size,
                              hipStream_t stream) {
    const float* x     = (const float*)d_in[0];
    const float* wqkv  = (const float*)d_in[1];
    const float* wproj = (const float*)d_in[2];
    const float* bproj = (const float*)d_in[3];
    const float* fcos  = (const float*)d_in[4];
    const float* fsin  = (const float*)d_in[5];
    float* out = (float*)d_out;

    bf16* x_bf     = (bf16*)d_ws;                       // 8192*1024
    bf16* wqkv_bf  = x_bf    + (size_t)M_ * C_;         // 3072*1024
    bf16* wproj_bf = wqkv_bf + (size_t)K3_ * C_;        // 1024*1024
    bf16* qbuf     = wproj_bf + (size_t)C_ * C_;        // 8192*1024 each
    bf16* kbuf     = qbuf  + (size_t)M_ * C_;
    bf16* vbuf     = kbuf  + (size_t)M_ * C_;
    bf16* abuf     = vbuf  + (size_t)M_ * C_;

    castk<<<2048, 256, 0, stream>>>(x,     x_bf,     M_ * C_ / 4);
    castk<<<1024, 256, 0, stream>>>(wqkv,  wqkv_bf,  K3_ * C_ / 4);
    castk<<<512,  256, 0, stream>>>(wproj, wproj_bf, C_ * C_ / 4);

    gemm_bt<0><<<64 * 24, 256, 0, stream>>>(x_bf, wqkv_bf, K3_, C_,
                                            qbuf, kbuf, vbuf, fcos, fsin, nullptr, nullptr);
    attn_kernel<<<64 * 32, 256, 0, stream>>>(qbuf, kbuf, vbuf, abuf);
    gemm_bt<1><<<64 * 8, 256, 0, stream>>>(abuf, wproj_bf, C_, C_,
                                           nullptr, nullptr, nullptr, nullptr, nullptr, bproj, out);
}

// Round 2
// 259.536 us; speedup vs baseline: 1.7110x; 1.7110x over previous
//
#include <hip/hip_runtime.h>
#include <hip/hip_bf16.h>
#include <stdint.h>

#define B_  4
#define N_  2048
#define C_  1024
#define H_  16
#define HD_ 64
#define M_  (B_*N_)     // 8192
#define K3_ (3*C_)      // 3072

typedef __bf16 bf16;
typedef __bf16 bf16x8 __attribute__((ext_vector_type(8)));
typedef __bf16 bf16x4 __attribute__((ext_vector_type(4)));
typedef float f32x4 __attribute__((ext_vector_type(4)));
typedef float f32x16 __attribute__((ext_vector_type(16)));

// ---------------- f32 -> bf16 cast ----------------
__global__ void castk(const float* __restrict__ in, bf16* __restrict__ out, int n4) {
    int stride = gridDim.x * blockDim.x;
    for (int i = blockIdx.x * blockDim.x + threadIdx.x; i < n4; i += stride) {
        float4 v = reinterpret_cast<const float4*>(in)[i];
        bf16x4 o;
        o[0] = (bf16)v.x; o[1] = (bf16)v.y; o[2] = (bf16)v.z; o[3] = (bf16)v.w;
        *reinterpret_cast<bf16x4*>(out + (size_t)i * 4) = o;
    }
}

__device__ __forceinline__ void gll16(const bf16* g, const bf16* l) {
    __builtin_amdgcn_global_load_lds(
        (const __attribute__((address_space(1))) void*)g,
        (__attribute__((address_space(3))) void*)l, 16, 0, 0);
}

__device__ __forceinline__ uint32_t pkbf(float a, float b) {
    uint16_t lo = __builtin_bit_cast(uint16_t, (bf16)a);
    uint16_t hi = __builtin_bit_cast(uint16_t, (bf16)b);
    return (uint32_t)lo | ((uint32_t)hi << 16);
}

__device__ __forceinline__ uint32_t pkraw(bf16 a, bf16 b) {
    uint16_t lo = __builtin_bit_cast(uint16_t, a);
    uint16_t hi = __builtin_bit_cast(uint16_t, b);
    return (uint32_t)lo | ((uint32_t)hi << 16);
}

// ---------------- GEMM  out[m][n] = sum_k A[m][k] * B[n][k] ----------------
template<int MODE>
__global__ __launch_bounds__(256, 2)
void gemm_bt(const bf16* __restrict__ A, const bf16* __restrict__ Bm,
             int Nn, int Kk,
             bf16* __restrict__ qout, bf16* __restrict__ kout, bf16* __restrict__ vout,
             const float* __restrict__ fcos, const float* __restrict__ fsin,
             const float* __restrict__ bias, float* __restrict__ Cout)
{
    __shared__ bf16 a_lds[128 * 32];
    __shared__ bf16 b_lds[128 * 32];
    const int tid  = threadIdx.x;
    const int lane = tid & 63;
    const int w    = tid >> 6;
    const int wr   = w >> 1, wc = w & 1;
    const int ntile = Nn >> 7;
    const int bx = blockIdx.x % ntile, by = blockIdx.x / ntile;
    const int m0 = by * 128, n0 = bx * 128;

    f32x4 acc[4][4] = {};

    const int c0 = tid, c1 = tid + 256;
    const bf16* ga0 = A  + (size_t)(m0 + (c0 >> 2)) * Kk + (c0 & 3) * 8;
    const bf16* ga1 = A  + (size_t)(m0 + (c1 >> 2)) * Kk + (c1 & 3) * 8;
    const bf16* gb0 = Bm + (size_t)(n0 + (c0 >> 2)) * Kk + (c0 & 3) * 8;
    const bf16* gb1 = Bm + (size_t)(n0 + (c1 >> 2)) * Kk + (c1 & 3) * 8;
    const bf16* la0 = a_lds + w * 512;
    const bf16* la1 = a_lds + w * 512 + 2048;
    const bf16* lb0 = b_lds + w * 512;
    const bf16* lb1 = b_lds + w * 512 + 2048;

    const int rA = lane & 15;
    const int kk = (lane >> 4) * 8;

    for (int k0 = 0; k0 < Kk; k0 += 32) {
        gll16(ga0 + k0, la0);
        gll16(ga1 + k0, la1);
        gll16(gb0 + k0, lb0);
        gll16(gb1 + k0, lb1);
        __syncthreads();

        bf16x8 af[4], bfr[4];
#pragma unroll
        for (int m = 0; m < 4; ++m)
            af[m] = *reinterpret_cast<const bf16x8*>(&a_lds[(wr * 64 + m * 16 + rA) * 32 + kk]);
#pragma unroll
        for (int n = 0; n < 4; ++n)
            bfr[n] = *reinterpret_cast<const bf16x8*>(&b_lds[(wc * 64 + n * 16 + rA) * 32 + kk]);
#pragma unroll
        for (int m = 0; m < 4; ++m)
#pragma unroll
            for (int n = 0; n < 4; ++n)
                acc[m][n] = __builtin_amdgcn_mfma_f32_16x16x32_bf16(af[m], bfr[n], acc[m][n], 0, 0, 0);
        __syncthreads();
    }

    if (MODE == 1) {
#pragma unroll
        for (int n = 0; n < 4; ++n) {
            int cg = n0 + wc * 64 + n * 16 + (lane & 15);
            float bv = bias[cg];
#pragma unroll
            for (int m = 0; m < 4; ++m) {
                int rg = m0 + wr * 64 + m * 16 + (lane >> 4) * 4;
#pragma unroll
                for (int r = 0; r < 4; ++r)
                    Cout[(size_t)(rg + r) * Nn + cg] = acc[m][n][r] + bv;
            }
        }
    } else {
        const int part = n0 >> 10;
#pragma unroll
        for (int n = 0; n < 4; ++n) {
            int cg  = n0 + wc * 64 + n * 16 + (lane & 15);
            int rem = cg & 1023;
            int h   = rem >> 6, hd = rem & 63;
#pragma unroll
            for (int m = 0; m < 4; ++m) {
#pragma unroll
                for (int r = 0; r < 4; ++r) {
                    int rg   = m0 + wr * 64 + m * 16 + (lane >> 4) * 4 + r;
                    int b    = rg >> 11, nrow = rg & 2047;
                    float val = acc[m][n][r];
                    size_t oi = ((size_t)(b * 16 + h) * N_ + nrow) * HD_ + hd;
                    if (part == 2) {
                        vout[oi] = (bf16)val;
                    } else {
                        float p   = __shfl_xor(val, 1);
                        float cth = fcos[nrow * 32 + (hd >> 1)];
                        float sth = fsin[nrow * 32 + (hd >> 1)];
                        float o   = (lane & 1) ? (val * cth + p * sth) : (val * cth - p * sth);
                        if (part == 0) { o *= 0.125f; qout[oi] = (bf16)o; }
                        else           { kout[oi] = (bf16)o; }
                    }
                }
            }
        }
    }
}

// ---------------- flash attention, 32x32 MFMA, swapped-QK^T in-register softmax ----
// q/k/v [B*H][N][HD] bf16 -> out [B][N][C] bf16. Q pre-scaled by 1/sqrt(HD).
__global__ __launch_bounds__(256, 3)
void attn_kernel(const bf16* __restrict__ Q, const bf16* __restrict__ Kb,
                 const bf16* __restrict__ Vb, bf16* __restrict__ Ob)
{
    __shared__ bf16 k_lds[64 * 64];   // K tile, rows swizzled: chunk c holds global chunk c^(row&7)
    __shared__ bf16 vt_lds[64 * 64];  // V^T tile, same swizzle
    const int tid = threadIdx.x, lane = tid & 63, w = tid >> 6;
    const int h5  = lane >> 5;        // half of wave
    const int l31 = lane & 31;
    const int nqt = N_ / 128;         // 16
    const int bh = blockIdx.x / nqt, qt = blockIdx.x % nqt;
    const size_t base = (size_t)bh * N_ * HD_;
    const int q0 = qt * 128 + w * 32;

    // Q fragments (B-operand): row q = lane&31, d = 16t + 8*h5 + 0..7
    bf16x8 qf[4];
    {
        const bf16* qp = Q + base + (size_t)(q0 + l31) * HD_ + h5 * 8;
#pragma unroll
        for (int t = 0; t < 4; ++t)
            qf[t] = *reinterpret_cast<const bf16x8*>(qp + t * 16);
    }

    f32x16 oT[2] = {};                // O^T: d reg-mapped, q = lane&31
    float m_run = -1e30f, l_run = 0.f;

    const int kp = tid & 31, dc = tid >> 5;   // V staging: k-pair, d-chunk

    for (int kv0 = 0; kv0 < N_; kv0 += 64) {
        // ---- stage K via global_load_lds, pre-swizzled source ----
        {
            int ca = tid, cb = tid + 256;
            const bf16* sa = Kb + base + (size_t)(kv0 + (ca >> 3)) * HD_ + (((ca & 7) ^ ((ca >> 3) & 7)) * 8);
            const bf16* sb = Kb + base + (size_t)(kv0 + (cb >> 3)) * HD_ + (((cb & 7) ^ ((cb >> 3) & 7)) * 8);
            gll16(sa, k_lds + w * 512);
            gll16(sb, k_lds + 2048 + w * 512);
        }
        // ---- stage V^T: pack k-pairs, swizzled ds_write_b32 ----
        {
            bf16x8 v0 = *reinterpret_cast<const bf16x8*>(Vb + base + (size_t)(kv0 + 2 * kp) * HD_ + dc * 8);
            bf16x8 v1 = *reinterpret_cast<const bf16x8*>(Vb + base + (size_t)(kv0 + 2 * kp + 1) * HD_ + dc * 8);
#pragma unroll
            for (int j = 0; j < 8; ++j) {
                int byteoff = (dc * 8 + j) * 128 + ((4 * kp) ^ (j << 4));
                *reinterpret_cast<uint32_t*>(reinterpret_cast<char*>(vt_lds) + byteoff) = pkraw(v0[j], v1[j]);
            }
        }
        __syncthreads();

        // ---- S^T = K Q^T : st[s] covers k rows kv0+32s..+31 (reg-mapped), q = lane&31 ----
        f32x16 st[2];
#pragma unroll
        for (int s = 0; s < 2; ++s) {
            f32x16 acc = {};
            int row = s * 32 + l31;
#pragma unroll
            for (int t = 0; t < 4; ++t) {
                int cc = (2 * t + h5) ^ (row & 7);
                bf16x8 kf = *reinterpret_cast<const bf16x8*>(
                    reinterpret_cast<const char*>(k_lds) + row * 128 + cc * 16);
                acc = __builtin_amdgcn_mfma_f32_32x32x16_bf16(kf, qf[t], acc, 0, 0, 0);
            }
            st[s] = acc;
        }

        // ---- online softmax, fully in-register (lane owns q-row lane&31) ----
        float pm = st[0][0];
#pragma unroll
        for (int i = 1; i < 16; ++i) pm = fmaxf(pm, st[0][i]);
#pragma unroll
        for (int i = 0; i < 16; ++i) pm = fmaxf(pm, st[1][i]);
        pm = fmaxf(pm, __shfl_xor(pm, 32));
        float nm    = fmaxf(m_run, pm);
        float alpha = __expf(m_run - nm);
        m_run = nm;
        float psum = 0.f;
#pragma unroll
        for (int s = 0; s < 2; ++s)
#pragma unroll
            for (int i = 0; i < 16; ++i) {
                float p = __expf(st[s][i] - nm);
                st[s][i] = p;
                psum += p;
            }
        psum += __shfl_xor(psum, 32);
        l_run = l_run * alpha + psum;
#pragma unroll
        for (int n = 0; n < 2; ++n)
#pragma unroll
            for (int i = 0; i < 16; ++i) oT[n][i] *= alpha;

        // ---- pack P to bf16 (k ascending within 4-groups) ----
        uint32_t pk2[8][2];
#pragma unroll
        for (int s = 0; s < 2; ++s)
#pragma unroll
            for (int g = 0; g < 4; ++g) {
                pk2[s * 4 + g][0] = pkbf(st[s][4 * g + 0], st[s][4 * g + 1]);
                pk2[s * 4 + g][1] = pkbf(st[s][4 * g + 2], st[s][4 * g + 3]);
            }
        // ---- build P fragments (B-operand of PV): chunk t covers k = 16t+8*h5+0..7 ----
        bf16x8 pf[4];
#pragma unroll
        for (int t = 0; t < 4; ++t) {
            const int gA = (t >> 1) * 4 + 2 * (t & 1);  // lower 8-group of this chunk
            const int gB = gA + 1;                      // upper 8-group
            uint32_t send0 = h5 ? pk2[gA][0] : pk2[gB][0];
            uint32_t send1 = h5 ? pk2[gA][1] : pk2[gB][1];
            uint32_t r0 = (uint32_t)__shfl_xor((int)send0, 32);
            uint32_t r1 = (uint32_t)__shfl_xor((int)send1, 32);
            union { uint32_t u[4]; bf16x8 v; } U;
            U.u[0] = h5 ? r0 : pk2[gA][0];
            U.u[1] = h5 ? r1 : pk2[gA][1];
            U.u[2] = h5 ? pk2[gB][0] : r0;
            U.u[3] = h5 ? pk2[gB][1] : r1;
            pf[t] = U.v;
        }

        // ---- O^T += V^T P^T : A = V^T rows (d = lane&31 within block), B = P ----
#pragma unroll
        for (int n = 0; n < 2; ++n) {
            int row = n * 32 + l31;
#pragma unroll
            for (int t = 0; t < 4; ++t) {
                int cc = (2 * t + h5) ^ (row & 7);
                bf16x8 vf = *reinterpret_cast<const bf16x8*>(
                    reinterpret_cast<const char*>(vt_lds) + row * 128 + cc * 16);
                oT[n] = __builtin_amdgcn_mfma_f32_32x32x16_bf16(vf, pf[t], oT[n], 0, 0, 0);
            }
        }
        __syncthreads();
    }

    // ---- epilogue: O[q][d] = oT / l_run, write [B][N][H*HD] bf16 ----
    const int b = bh >> 4, hh = bh & 15;
    float inv = 1.0f / l_run;
    int q = q0 + l31;
#pragma unroll
    for (int n = 0; n < 2; ++n)
#pragma unroll
        for (int g = 0; g < 4; ++g) {
            int d = n * 32 + 8 * g + 4 * h5;
            bf16x4 o4;
#pragma unroll
            for (int r = 0; r < 4; ++r) o4[r] = (bf16)(oT[n][4 * g + r] * inv);
            *reinterpret_cast<bf16x4*>(Ob + ((size_t)(b * N_ + q)) * C_ + hh * 64 + d) = o4;
        }
}

extern "C" void kernel_launch(void* const* d_in, const int* in_sizes, int n_in,
                              void* d_out, int out_size, void* d_ws, size_t ws_size,
                              hipStream_t stream) {
    const float* x     = (const float*)d_in[0];
    const float* wqkv  = (const float*)d_in[1];
    const float* wproj = (const float*)d_in[2];
    const float* bproj = (const float*)d_in[3];
    const float* fcos  = (const float*)d_in[4];
    const float* fsin  = (const float*)d_in[5];
    float* out = (float*)d_out;

    bf16* x_bf     = (bf16*)d_ws;
    bf16* wqkv_bf  = x_bf    + (size_t)M_ * C_;
    bf16* wproj_bf = wqkv_bf + (size_t)K3_ * C_;
    bf16* qbuf     = wproj_bf + (size_t)C_ * C_;
    bf16* kbuf     = qbuf  + (size_t)M_ * C_;
    bf16* vbuf     = kbuf  + (size_t)M_ * C_;
    bf16* abuf     = vbuf  + (size_t)M_ * C_;

    castk<<<2048, 256, 0, stream>>>(x,     x_bf,     M_ * C_ / 4);
    castk<<<1024, 256, 0, stream>>>(wqkv,  wqkv_bf,  K3_ * C_ / 4);
    castk<<<512,  256, 0, stream>>>(wproj, wproj_bf, C_ * C_ / 4);

    gemm_bt<0><<<64 * 24, 256, 0, stream>>>(x_bf, wqkv_bf, K3_, C_,
                                            qbuf, kbuf, vbuf, fcos, fsin, nullptr, nullptr);
    attn_kernel<<<64 * 16, 256, 0, stream>>>(qbuf, kbuf, vbuf, abuf);
    gemm_bt<1><<<64 * 8, 256, 0, stream>>>(abuf, wproj_bf, C_, C_,
                                           nullptr, nullptr, nullptr, nullptr, nullptr, bproj, out);
}